// Round 11
// baseline (90.693 us; speedup 1.0000x reference)
//
#include <hip/hip_runtime.h>

#define N_CELLS   16384
#define N_CLASSES 64
#define BATCH     64
#define CPB       4   // cells per block

typedef float f32x4 __attribute__((ext_vector_type(4)));

// 1.7159 * tanh((2/3)*s)  — sign-safe fast form.
__device__ __forceinline__ float agm_act(float s) {
    float az = fabsf(s);
    float e  = __expf(-1.3333333333f * az);      // in (0,1], no overflow
    float t  = __fdividef(1.0f - e, 1.0f + e);   // rcp + mul, ~1 ulp
    return copysignf(1.7159f * t, s);
}

// R3 champion structure. Single change: two-phase body.
// Phase 1 issues ALL 48 x-loads (registers, full unroll, static idx);
// phase 2 does 16 pure compute+NT-store iterations. Rationale: vmcnt is
// in-order and shared by loads+stores; in R3 each iteration's load-waitcnt
// also waited on the previous iteration's NT-store ack (slow when the
// write path is saturated). With no load after any store, that stall
// disappears.
__global__ __launch_bounds__(256, 4) void mnl_kernel(
    const float* __restrict__ x,     // (B, N)
    const float* __restrict__ w,     // (N, C, 3)
    const float* __restrict__ bias,  // (N, C)
    float* __restrict__ out)         // (B, N, C)
{
    const int t    = threadIdx.x;
    const int lane = t & 63;
    const int wid  = t >> 6;              // wave id 0..3 -> batch phase
    const int di   = lane >> 4;           // cell within block, 0..3
    const int c4   = (lane & 15) * 4;     // class group
    const int i    = blockIdx.x * CPB + di;

    const int il = (i == 0)           ? N_CELLS - 1 : i - 1;
    const int ir = (i == N_CELLS - 1) ? 0           : i + 1;

    // ---- per-thread weights: 12 consecutive floats (16B aligned) ----
    const float4* wv = reinterpret_cast<const float4*>(
        w + (size_t)i * (N_CLASSES * 3) + (size_t)c4 * 3);
    const float4 v0 = wv[0], v1 = wv[1], v2 = wv[2];
    const float wr[12] = { v0.x, v0.y, v0.z, v0.w,
                           v1.x, v1.y, v1.z, v1.w,
                           v2.x, v2.y, v2.z, v2.w };

    const float4 bi = *reinterpret_cast<const float4*>(
        bias + (size_t)i * N_CLASSES + c4);
    const float bj[4] = { bi.x, bi.y, bi.z, bi.w };

    // ---- phase 1: all x loads up front (48 regs, static indices) ----
    float xl[16], xc[16], xr[16];
    #pragma unroll
    for (int p = 0; p < 16; ++p) {
        const int b = p * 4 + wid;
        const size_t xb = (size_t)b * N_CELLS;
        xl[p] = x[xb + il];
        xc[p] = x[xb + i];
        xr[p] = x[xb + ir];
    }

    __builtin_amdgcn_sched_barrier(0);   // keep loads above all stores

    // ---- phase 2: pure compute + NT store stream ----
    #pragma unroll
    for (int p = 0; p < 16; ++p) {
        const int b = p * 4 + wid;

        f32x4 o;
        o.x = agm_act(fmaf(xl[p], wr[0], fmaf(xc[p], wr[1],  fmaf(xr[p], wr[2],  bj[0]))));
        o.y = agm_act(fmaf(xl[p], wr[3], fmaf(xc[p], wr[4],  fmaf(xr[p], wr[5],  bj[1]))));
        o.z = agm_act(fmaf(xl[p], wr[6], fmaf(xc[p], wr[7],  fmaf(xr[p], wr[8],  bj[2]))));
        o.w = agm_act(fmaf(xl[p], wr[9], fmaf(xc[p], wr[10], fmaf(xr[p], wr[11], bj[3]))));

        f32x4* op = reinterpret_cast<f32x4*>(
            out + ((size_t)b * N_CELLS + i) * N_CLASSES + c4);
        __builtin_nontemporal_store(o, op);
    }
}

extern "C" void kernel_launch(void* const* d_in, const int* in_sizes, int n_in,
                              void* d_out, int out_size, void* d_ws, size_t ws_size,
                              hipStream_t stream) {
    const float* x    = (const float*)d_in[0];  // (64, 16384, 1)
    const float* w    = (const float*)d_in[1];  // (16384, 64, 3)
    const float* bias = (const float*)d_in[2];  // (16384, 64)
    float* out = (float*)d_out;                 // (64, 16384, 64)

    dim3 grid(N_CELLS / CPB);
    dim3 block(256);
    mnl_kernel<<<grid, block, 0, stream>>>(x, w, bias, out);
}